// Round 5
// baseline (319.885 us; speedup 1.0000x reference)
//
#include <hip/hip_runtime.h>
#include <hip/hip_cooperative_groups.h>
#include <math.h>

namespace cg = cooperative_groups;

// Legendre-KAN: y[n,o] = sum_{i,d} P_d(xn[n,i]) * coeffs[o,i,d] + bias[o]
// GEMM: A[65536 x 4096] (on-the-fly scaled-Legendre basis, bf16) * B[4096 x 64] (bf16).
//
// R5: single cooperative kernel (512 blocks x 256 thr, 2/CU co-resident).
//   phase 0: B-prep (blocks<128) + min/max over the block's OWN 128-row slice
//            (warms local L2 with exactly the rows phase 2 stages) + issue
//            chunk-0 gload_lds (completes during grid sync wait).
//   grid.sync() (device-scope fence: Bws + partials visible).
//   phase 1: reduce 512 partials/wave -> s,off; R4 GEMM structure unchanged.
// Purpose: (a) one ~80us dispatch -> top-5 counter visibility (k_main was never
// profiled; fills mask <77us); (b) kill launch gap + warm x. Fallback to the
// R4 two-kernel path if cooperative launch is refused.

typedef __bf16 bf16x8 __attribute__((ext_vector_type(8)));
typedef float f32x4 __attribute__((ext_vector_type(4)));

__device__ __forceinline__ void gload_lds16(const float* g, void* lds) {
  // dest = wave-uniform base + lane*16 (linear); source is per-lane.
  __builtin_amdgcn_global_load_lds(
      static_cast<const unsigned int*>(static_cast<const void*>(g)),
      static_cast<unsigned int*>(lds), 16, 0, 0);
}

__device__ __forceinline__ void bprep_tile(const float* __restrict__ coeffs,
                                           bf16x8* __restrict__ Bws, int t) {
  // Bws[(kt*4+ct)*64 + lane][j] = coeffs[o=ct*16+(lane&15)][i=kt*4+(lane>>4)][d=j]*g[j]
  int lane = t & 63;
  int tile = t >> 6;                        // kt*4 + ct
  int ct = tile & 3;
  int kt = tile >> 2;
  int ii = kt * 4 + (lane >> 4);
  int o  = ct * 16 + (lane & 15);
  const float4* cp = (const float4*)(coeffs + ((size_t)o * 512 + ii) * 8);
  float4 c0 = cp[0], c1 = cp[1];
  // g_n: P_n = g_n * S_n;  g = {1,1,1.5,2.5,4.375,7.875,14.4375,26.8125}
  bf16x8 v;
  v[0] = (__bf16)(c0.x);
  v[1] = (__bf16)(c0.y);
  v[2] = (__bf16)(c0.z * 1.5f);
  v[3] = (__bf16)(c0.w * 2.5f);
  v[4] = (__bf16)(c1.x * 4.375f);
  v[5] = (__bf16)(c1.y * 7.875f);
  v[6] = (__bf16)(c1.z * 14.4375f);
  v[7] = (__bf16)(c1.w * 26.8125f);
  Bws[(size_t)(kt * 4 + ct) * 64 + lane] = v;
}

// ==================== fused cooperative kernel ====================
// LDS x-buffer: 2 x [128 rows][64 cols] f32 (32 KiB each), linear, swizzled:
//   phys float4-slot(row, cf) holds logical cf ^ (row & 15).
// Read (per kt, per f 0..7): float idx = (f*16+m)*64 + ((4w+ktl)^m)*4 + quad
//   -> bank 4*(((4w+ktl)^m)&7) + quad: 2 lanes/bank = free.
#define NBLK 512
__global__ __launch_bounds__(256, 2) void k_fused(
    const float* __restrict__ x, const float* __restrict__ coeffs,
    const float* __restrict__ bias, float* __restrict__ pmn,
    float* __restrict__ pmx, bf16x8* __restrict__ Bws, float* __restrict__ y)
{
  __shared__ __attribute__((aligned(16))) char smem[65536]; // 2x32K stage; 48K reduce (reuse)

  const int t    = threadIdx.x;
  const int lane = t & 63;
  const int w    = t >> 6;
  const int m    = lane & 15;
  const int quad = lane >> 4;
  const size_t blockRow = (size_t)blockIdx.x * 128;

  // ---- phase 0a: B prep (blocks < 128; 128*256 threads cover 32768 tiles) ----
  if (blockIdx.x < 128)
    bprep_tile(coeffs, Bws, blockIdx.x * 256 + t);

  // ---- phase 0b: min/max over OWN 128-row slice (64 float4/thread, coalesced;
  //      warms this CU's XCD-L2 with exactly the rows phase 2 will stage) ----
  {
    const float4* xt = (const float4*)(x + blockRow * 512);
    float mn = 3.4e38f, mx = -3.4e38f;
    #pragma unroll 8
    for (int i = t; i < 16384; i += 256) {
      float4 v = xt[i];
      mn = fminf(mn, fminf(fminf(v.x, v.y), fminf(v.z, v.w)));
      mx = fmaxf(mx, fmaxf(fmaxf(v.x, v.y), fmaxf(v.z, v.w)));
    }
    #pragma unroll
    for (int o2 = 32; o2 > 0; o2 >>= 1) {
      mn = fminf(mn, __shfl_down(mn, o2));
      mx = fmaxf(mx, __shfl_down(mx, o2));
    }
    float* sred = (float*)(smem + 32768);   // buf1 region, unused until chunk 1
    if (lane == 0) { sred[w] = mn; sred[4 + w] = mx; }
    __syncthreads();
    if (t == 0) {
      pmn[blockIdx.x] = fminf(fminf(sred[0], sred[1]), fminf(sred[2], sred[3]));
      pmx[blockIdx.x] = fmaxf(fmaxf(sred[4], sred[5]), fmaxf(sred[6], sred[7]));
    }
  }

  // per-lane global source pointers for the 8 staging instructions (chunk-invariant)
  const float* gp[8];
  #pragma unroll
  for (int p = 0; p < 8; ++p) {
    int r15 = (4 * p + quad) & 15;   // row & 15
    int row = 32 * w + 4 * p + quad;
    int cfl = m ^ r15;               // source float4-col = phys ^ (row&15)
    gp[p] = x + (size_t)(blockRow + row) * 512 + cfl * 4;
  }
  // issue chunk-0 stage now; completes while we wait in grid.sync()
  #pragma unroll
  for (int p = 0; p < 8; ++p)
    gload_lds16(gp[p], smem + (w * 8 + p) * 1024);

  cg::this_grid().sync();            // Bws + partials visible device-wide

  // ---- phase 1a: per-wave reduce of the 512 partials -> s, off ----
  float mn = 3.4e38f, mx = -3.4e38f;
  #pragma unroll
  for (int j = 0; j < NBLK / 64; ++j) {
    mn = fminf(mn, pmn[lane + j * 64]);
    mx = fmaxf(mx, pmx[lane + j * 64]);
  }
  #pragma unroll
  for (int o2 = 32; o2 > 0; o2 >>= 1) {
    mn = fminf(mn, __shfl_xor(mn, o2));
    mx = fmaxf(mx, __shfl_xor(mx, o2));
  }
  const float s   = 2.0f / (mx - mn);
  const float off = fmaf(-mn, s, -1.0f);   // xn = x*s + off

  // B ring: 2 slots, distance-1. slot = l&1 (ktl&1: compile-time static).
  bf16x8 Bq[2][4];
  #pragma unroll
  for (int ct = 0; ct < 4; ++ct)
    Bq[0][ct] = Bws[(size_t)((4 * w + 0) * 4 + ct) * 64 + lane];

  f32x4 acc[8][4];
  #pragma unroll
  for (int f = 0; f < 8; ++f)
    #pragma unroll
    for (int ct = 0; ct < 4; ++ct) acc[f][ct] = (f32x4){0.f, 0.f, 0.f, 0.f};

  int xbase[8], xo[4];
  #pragma unroll
  for (int f = 0; f < 8; ++f) xbase[f] = (f * 16 + m) * 64 + quad;
  #pragma unroll
  for (int k = 0; k < 4; ++k) xo[k] = ((4 * w + k) ^ m) << 2;

  // scaled-recurrence constants c_n = b_n*g_{n-2}/g_n  (S_n = xn*S_{n-1} - c_n*S_{n-2})
  const float C2 = 0.33333334f, C3 = 0.26666668f, C4 = 0.25714287f;
  const float C5 = 0.25396827f, C6 = 0.25252524f, C7 = 0.25174826f;

  __syncthreads();   // chunk-0 stage drained (finished during grid sync)

  for (int c = 0; c < 8; ++c) {          // 8 chunks x (4 kt/wave) = 32 kt/wave
    const float* xr = (const float*)(smem + (c & 1) * 32768);

    if (c < 7) {                         // issue next chunk's stage into other buffer
      char* lb = smem + ((c + 1) & 1) * 32768;
      #pragma unroll
      for (int p = 0; p < 8; ++p)
        gload_lds16(gp[p] + (c + 1) * 64, lb + (w * 8 + p) * 1024);
    }

    float xvv[2][8];
    #pragma unroll
    for (int f = 0; f < 8; ++f) xvv[0][f] = xr[xbase[f] + xo[0]];

    #pragma unroll
    for (int ktl = 0; ktl < 4; ++ktl) {
      const int l = c * 4 + ktl;         // local kt in [0,32)

      { // B prefetch distance 1, 2-slot ring (slot = l&1, static per ktl)
        const int lp  = (l + 1) & 31;
        const int ktg = ((lp >> 2) << 4) + 4 * w + (lp & 3);   // global kt
        #pragma unroll
        for (int ct = 0; ct < 4; ++ct)
          Bq[(ktl + 1) & 1][ct] = Bws[(size_t)(ktg * 4 + ct) * 64 + lane];
      }
      if (ktl < 3) {
        #pragma unroll
        for (int f = 0; f < 8; ++f)
          xvv[(ktl + 1) & 1][f] = xr[xbase[f] + xo[ktl + 1]];
      }

      #pragma unroll
      for (int f = 0; f < 8; ++f) {
        float xn = fmaf(xvv[ktl & 1][f], s, off);
        float s2 = fmaf(xn, xn, -C2);
        float s3 = (s2 - C3) * xn;
        float s4 = fmaf(xn, s3, -(C4 * s2));
        float s5 = fmaf(xn, s4, -(C5 * s3));
        float s6 = fmaf(xn, s5, -(C6 * s4));
        float s7 = fmaf(xn, s6, -(C7 * s5));
        bf16x8 av;
        av[0] = (__bf16)1.0f; av[1] = (__bf16)xn; av[2] = (__bf16)s2; av[3] = (__bf16)s3;
        av[4] = (__bf16)s4;   av[5] = (__bf16)s5; av[6] = (__bf16)s6; av[7] = (__bf16)s7;
        #pragma unroll
        for (int ct = 0; ct < 4; ++ct)
          acc[f][ct] = __builtin_amdgcn_mfma_f32_16x16x32_bf16(av, Bq[ktl & 1][ct], acc[f][ct], 0, 0, 0);
      }
    }
    __syncthreads();   // next-chunk stage complete AND all waves done reading this buffer
  }

  // ---- epilogue: 2 rounds x all-wave parallel reduce (48 KiB), acc static ----
  f32x4* red = (f32x4*)smem;
  float bv0 = bias[m], bv1 = bias[16 + m], bv2 = bias[32 + m], bv3 = bias[48 + m];
  #pragma unroll
  for (int r = 0; r < 2; ++r) {
    if (r == 1) __syncthreads();         // round-0 reads done before overwriting red
    #pragma unroll
    for (int g2 = 0; g2 < 4; ++g2) {
      if (g2 != w) {                     // wave-uniform; indices unroll-static
        int slot = w - (w > g2 ? 1 : 0);
        #pragma unroll
        for (int ct = 0; ct < 4; ++ct)
          red[(size_t)g2 * 768 + slot * 256 + ct * 64 + lane] = acc[r * 4 + g2][ct];
      }
    }
    __syncthreads();
    #pragma unroll
    for (int g2 = 0; g2 < 4; ++g2) {
      if (g2 == w) {                     // wave-uniform; acc[r*4+g2] static (rule #20)
        f32x4 vv[4];
        #pragma unroll
        for (int ct = 0; ct < 4; ++ct) {
          f32x4 v = acc[r * 4 + g2][ct];
          v += red[(size_t)g2 * 768 + 0 * 256 + ct * 64 + lane];
          v += red[(size_t)g2 * 768 + 1 * 256 + ct * 64 + lane];
          v += red[(size_t)g2 * 768 + 2 * 256 + ct * 64 + lane];
          vv[ct] = v;
        }
        // C/D layout: col = m, row = quad*4 + rr ; rows [(r*4+g2)*16, +16)
        float* yp = y + (blockRow + (r * 4 + g2) * 16 + quad * 4) * 64 + m;
        #pragma unroll
        for (int rr = 0; rr < 4; ++rr) {
          float* ypr = yp + rr * 64;
          ypr[0]  = vv[0][rr] + bv0;
          ypr[16] = vv[1][rr] + bv1;
          ypr[32] = vv[2][rr] + bv2;
          ypr[48] = vv[3][rr] + bv3;
        }
      }
    }
  }
}

// ==================== fallback path (R4 structure, proven) ====================
#define NPART 2048
__global__ __launch_bounds__(256) void k_pre(
    const float4* __restrict__ x4, int n4,
    float* __restrict__ pmn, float* __restrict__ pmx,
    const float* __restrict__ coeffs, bf16x8* __restrict__ Bws, int doprep)
{
  if (doprep && blockIdx.x < 128)
    bprep_tile(coeffs, Bws, blockIdx.x * 256 + threadIdx.x);
  float mn = 3.4e38f, mx = -3.4e38f;
  int stride = gridDim.x * 256;
  for (int i = blockIdx.x * 256 + threadIdx.x; i < n4; i += stride) {
    float4 v = x4[i];
    mn = fminf(mn, fminf(fminf(v.x, v.y), fminf(v.z, v.w)));
    mx = fmaxf(mx, fmaxf(fmaxf(v.x, v.y), fmaxf(v.z, v.w)));
  }
  #pragma unroll
  for (int off = 32; off > 0; off >>= 1) {
    mn = fminf(mn, __shfl_down(mn, off));
    mx = fmaxf(mx, __shfl_down(mx, off));
  }
  __shared__ float smn[4], smx[4];
  int w = threadIdx.x >> 6;
  if ((threadIdx.x & 63) == 0) { smn[w] = mn; smx[w] = mx; }
  __syncthreads();
  if (threadIdx.x == 0) {
    pmn[blockIdx.x] = fminf(fminf(smn[0], smn[1]), fminf(smn[2], smn[3]));
    pmx[blockIdx.x] = fmaxf(fmaxf(smx[0], smx[1]), fmaxf(smx[2], smx[3]));
  }
}

__global__ __launch_bounds__(256, 2) void k_main(
    const float* __restrict__ x, const bf16x8* __restrict__ Bws,
    const float* __restrict__ bias, const float* __restrict__ pmn,
    const float* __restrict__ pmx, float* __restrict__ y)
{
  __shared__ __attribute__((aligned(16))) char smem[65536];

  const int t    = threadIdx.x;
  const int lane = t & 63;
  const int w    = t >> 6;
  const int m    = lane & 15;
  const int quad = lane >> 4;
  const size_t blockRow = (size_t)blockIdx.x * 128;

  const float* gp[8];
  #pragma unroll
  for (int p = 0; p < 8; ++p) {
    int r15 = (4 * p + quad) & 15;
    int row = 32 * w + 4 * p + quad;
    int cfl = m ^ r15;
    gp[p] = x + (size_t)(blockRow + row) * 512 + cfl * 4;
  }
  #pragma unroll
  for (int p = 0; p < 8; ++p)
    gload_lds16(gp[p], smem + (w * 8 + p) * 1024);

  float mn = 3.4e38f, mx = -3.4e38f;
  #pragma unroll
  for (int j = 0; j < NPART / 64; ++j) {
    mn = fminf(mn, pmn[lane + j * 64]);
    mx = fmaxf(mx, pmx[lane + j * 64]);
  }
  #pragma unroll
  for (int o2 = 32; o2 > 0; o2 >>= 1) {
    mn = fminf(mn, __shfl_xor(mn, o2));
    mx = fmaxf(mx, __shfl_xor(mx, o2));
  }
  const float s   = 2.0f / (mx - mn);
  const float off = fmaf(-mn, s, -1.0f);

  bf16x8 Bq[2][4];
  #pragma unroll
  for (int ct = 0; ct < 4; ++ct)
    Bq[0][ct] = Bws[(size_t)((4 * w + 0) * 4 + ct) * 64 + lane];

  f32x4 acc[8][4];
  #pragma unroll
  for (int f = 0; f < 8; ++f)
    #pragma unroll
    for (int ct = 0; ct < 4; ++ct) acc[f][ct] = (f32x4){0.f, 0.f, 0.f, 0.f};

  int xbase[8], xo[4];
  #pragma unroll
  for (int f = 0; f < 8; ++f) xbase[f] = (f * 16 + m) * 64 + quad;
  #pragma unroll
  for (int k = 0; k < 4; ++k) xo[k] = ((4 * w + k) ^ m) << 2;

  const float C2 = 0.33333334f, C3 = 0.26666668f, C4 = 0.25714287f;
  const float C5 = 0.25396827f, C6 = 0.25252524f, C7 = 0.25174826f;

  __syncthreads();

  for (int c = 0; c < 8; ++c) {
    const float* xr = (const float*)(smem + (c & 1) * 32768);
    if (c < 7) {
      char* lb = smem + ((c + 1) & 1) * 32768;
      #pragma unroll
      for (int p = 0; p < 8; ++p)
        gload_lds16(gp[p] + (c + 1) * 64, lb + (w * 8 + p) * 1024);
    }
    float xvv[2][8];
    #pragma unroll
    for (int f = 0; f < 8; ++f) xvv[0][f] = xr[xbase[f] + xo[0]];
    #pragma unroll
    for (int ktl = 0; ktl < 4; ++ktl) {
      const int l = c * 4 + ktl;
      {
        const int lp  = (l + 1) & 31;
        const int ktg = ((lp >> 2) << 4) + 4 * w + (lp & 3);
        #pragma unroll
        for (int ct = 0; ct < 4; ++ct)
          Bq[(ktl + 1) & 1][ct] = Bws[(size_t)(ktg * 4 + ct) * 64 + lane];
      }
      if (ktl < 3) {
        #pragma unroll
        for (int f = 0; f < 8; ++f)
          xvv[(ktl + 1) & 1][f] = xr[xbase[f] + xo[ktl + 1]];
      }
      #pragma unroll
      for (int f = 0; f < 8; ++f) {
        float xn = fmaf(xvv[ktl & 1][f], s, off);
        float s2 = fmaf(xn, xn, -C2);
        float s3 = (s2 - C3) * xn;
        float s4 = fmaf(xn, s3, -(C4 * s2));
        float s5 = fmaf(xn, s4, -(C5 * s3));
        float s6 = fmaf(xn, s5, -(C6 * s4));
        float s7 = fmaf(xn, s6, -(C7 * s5));
        bf16x8 av;
        av[0] = (__bf16)1.0f; av[1] = (__bf16)xn; av[2] = (__bf16)s2; av[3] = (__bf16)s3;
        av[4] = (__bf16)s4;   av[5] = (__bf16)s5; av[6] = (__bf16)s6; av[7] = (__bf16)s7;
        #pragma unroll
        for (int ct = 0; ct < 4; ++ct)
          acc[f][ct] = __builtin_amdgcn_mfma_f32_16x16x32_bf16(av, Bq[ktl & 1][ct], acc[f][ct], 0, 0, 0);
      }
    }
    __syncthreads();
  }

  f32x4* red = (f32x4*)smem;
  float bv0 = bias[m], bv1 = bias[16 + m], bv2 = bias[32 + m], bv3 = bias[48 + m];
  #pragma unroll
  for (int r = 0; r < 2; ++r) {
    if (r == 1) __syncthreads();
    #pragma unroll
    for (int g2 = 0; g2 < 4; ++g2) {
      if (g2 != w) {
        int slot = w - (w > g2 ? 1 : 0);
        #pragma unroll
        for (int ct = 0; ct < 4; ++ct)
          red[(size_t)g2 * 768 + slot * 256 + ct * 64 + lane] = acc[r * 4 + g2][ct];
      }
    }
    __syncthreads();
    #pragma unroll
    for (int g2 = 0; g2 < 4; ++g2) {
      if (g2 == w) {
        f32x4 vv[4];
        #pragma unroll
        for (int ct = 0; ct < 4; ++ct) {
          f32x4 v = acc[r * 4 + g2][ct];
          v += red[(size_t)g2 * 768 + 0 * 256 + ct * 64 + lane];
          v += red[(size_t)g2 * 768 + 1 * 256 + ct * 64 + lane];
          v += red[(size_t)g2 * 768 + 2 * 256 + ct * 64 + lane];
          vv[ct] = v;
        }
        float* yp = y + (blockRow + (r * 4 + g2) * 16 + quad * 4) * 64 + m;
        #pragma unroll
        for (int rr = 0; rr < 4; ++rr) {
          float* ypr = yp + rr * 64;
          ypr[0]  = vv[0][rr] + bv0;
          ypr[16] = vv[1][rr] + bv1;
          ypr[32] = vv[2][rr] + bv2;
          ypr[48] = vv[3][rr] + bv3;
        }
      }
    }
  }
}

// ---------------- last-resort fallback (no workspace for Bws) ----------
__global__ __launch_bounds__(256) void k_so(
    const float* __restrict__ pmn, const float* __restrict__ pmx, int nb,
    float* __restrict__ so)
{
  float mn = 3.4e38f, mx = -3.4e38f;
  for (int i = threadIdx.x; i < nb; i += 256) {
    mn = fminf(mn, pmn[i]);
    mx = fmaxf(mx, pmx[i]);
  }
  #pragma unroll
  for (int off = 32; off > 0; off >>= 1) {
    mn = fminf(mn, __shfl_down(mn, off));
    mx = fmaxf(mx, __shfl_down(mx, off));
  }
  __shared__ float smn[4], smx[4];
  int w = threadIdx.x >> 6;
  if ((threadIdx.x & 63) == 0) { smn[w] = mn; smx[w] = mx; }
  __syncthreads();
  if (threadIdx.x == 0) {
    mn = fminf(fminf(smn[0], smn[1]), fminf(smn[2], smn[3]));
    mx = fmaxf(fmaxf(smx[0], smx[1]), fmaxf(smx[2], smx[3]));
    float r = mx - mn;
    so[0] = 2.0f / r;
    so[1] = -2.0f * mn / r - 1.0f;
  }
}

__global__ __launch_bounds__(256) void k_main_simple(
    const float* __restrict__ x, const float* __restrict__ coeffs,
    const float* __restrict__ bias, const float* __restrict__ so, float* __restrict__ y)
{
  const float s = so[0], off = so[1];
  const int lane = threadIdx.x & 63;
  const int w    = threadIdx.x >> 6;
  const int m    = lane & 15;
  const int quad = lane >> 4;
  const int rowA = blockIdx.x * 64 + w * 16 + m;
  const float* xp = x + (size_t)rowA * 512 + quad;

  f32x4 acc0 = {0.f,0.f,0.f,0.f}, acc1 = acc0, acc2 = acc0, acc3 = acc0;
  const float c3a = 5.f/3.f, c3b = 2.f/3.f, c6a = 11.f/6.f, c6b = 5.f/6.f, c7a = 13.f/7.f, c7b = 6.f/7.f;

  for (int kt = 0; kt < 128; ++kt) {
    float xv = xp[kt * 4];
    int i = kt * 4 + quad;
    bf16x8 b[4];
    #pragma unroll
    for (int ct = 0; ct < 4; ++ct) {
      const float* cp = coeffs + ((size_t)(ct * 16 + m) * 512 + i) * 8;
      #pragma unroll
      for (int j = 0; j < 8; ++j) b[ct][j] = (__bf16)cp[j];
    }
    float xn = fmaf(xv, s, off);
    float p2 = fmaf(1.5f * xn, xn, -0.5f);
    float p3 = fmaf(c3a * xn, p2, -(c3b * xn));
    float p4 = fmaf(1.75f * xn, p3, -(0.75f * p2));
    float p5 = fmaf(1.8f * xn, p4, -(0.8f * p3));
    float p6 = fmaf(c6a * xn, p5, -(c6b * p4));
    float p7 = fmaf(c7a * xn, p6, -(c7b * p5));
    bf16x8 a;
    a[0] = (__bf16)1.0f; a[1] = (__bf16)xn; a[2] = (__bf16)p2; a[3] = (__bf16)p3;
    a[4] = (__bf16)p4;   a[5] = (__bf16)p5; a[6] = (__bf16)p6; a[7] = (__bf16)p7;
    acc0 = __builtin_amdgcn_mfma_f32_16x16x32_bf16(a, b[0], acc0, 0, 0, 0);
    acc1 = __builtin_amdgcn_mfma_f32_16x16x32_bf16(a, b[1], acc1, 0, 0, 0);
    acc2 = __builtin_amdgcn_mfma_f32_16x16x32_bf16(a, b[2], acc2, 0, 0, 0);
    acc3 = __builtin_amdgcn_mfma_f32_16x16x32_bf16(a, b[3], acc3, 0, 0, 0);
  }
  float b0v = bias[m], b1v = bias[16+m], b2v = bias[32+m], b3v = bias[48+m];
  float* yp = y + ((size_t)(blockIdx.x * 64 + w * 16 + quad * 4)) * 64 + m;
  #pragma unroll
  for (int r = 0; r < 4; ++r) {
    yp[r*64+ 0] = acc0[r] + b0v;
    yp[r*64+16] = acc1[r] + b1v;
    yp[r*64+32] = acc2[r] + b2v;
    yp[r*64+48] = acc3[r] + b3v;
  }
}

extern "C" void kernel_launch(void* const* d_in, const int* in_sizes, int n_in,
                              void* d_out, int out_size, void* d_ws, size_t ws_size,
                              hipStream_t stream)
{
  const float* x      = (const float*)d_in[0];
  const float* coeffs = (const float*)d_in[1];
  const float* bias   = (const float*)d_in[2];
  float* y = (float*)d_out;

  long nx = (long)in_sizes[0];        // 33,554,432
  int  N  = (int)(nx / 512);          // 65536 rows
  int  n4 = (int)(nx / 4);

  float*  so  = (float*)d_ws;
  float*  pmn = (float*)d_ws + 16;
  float*  pmx = pmn + 4096;
  bf16x8* Bws = (bf16x8*)((char*)d_ws + 65536);

  bool pre = ws_size >= (size_t)(65536 + 4096 * 64 * 2 + 4096);
  if (pre && N == 65536) {
    void* args[] = {(void*)&x, (void*)&coeffs, (void*)&bias,
                    (void*)&pmn, (void*)&pmx, (void*)&Bws, (void*)&y};
    hipError_t e = hipLaunchCooperativeKernel((const void*)k_fused,
                                              dim3(NBLK), dim3(256), args, 0, stream);
    if (e == hipSuccess) return;
    (void)hipGetLastError();         // clear; fall through to 2-kernel path
  }
  k_pre<<<NPART, 256, 0, stream>>>((const float4*)x, n4, pmn, pmx, coeffs, Bws, pre ? 1 : 0);
  if (pre) {
    k_main<<<N / 128, 256, 0, stream>>>(x, Bws, bias, pmn, pmx, y);
  } else {
    k_so<<<1, 256, 0, stream>>>(pmn, pmx, NPART, so);
    k_main_simple<<<N / 64, 256, 0, stream>>>(x, coeffs, bias, so, y);
  }
}